// Round 11
// baseline (378.709 us; speedup 1.0000x reference)
//
#include <hip/hip_runtime.h>
#include <stdint.h>

// ============================================================================
// LaneGraphConvLayerShared: NNConv(edge-conditioned) + root + residual + LN
//
// msg[e] = sum_{s<16} a[e,s]*(x[src]@W_s) + x[src]@Bb   (Bb = reshape(b_edge))
//
// R9/R10 post-mortem: identical absmax 5.203125 in both -> structural bug,
//   not machinery: in one-wave-one-tile, wave w only computed f-cols
//   [16w,16w+16) of ITS OWN tile -> 3/4 of every tile's output missing
//   (the m225/m226 wave->output-tile decomposition mistake).
// R11: fix = each wave computes ALL 64 f-cols of its tile, c-loop 0..3
//   (unroll 1, ~125 live VGPRs, no spill). Per-tile work identical to R7,
//   but owned by ONE barrier-free wave (tests the decoupling theory).
//   - zero LDS / barriers / cross-lane ops in the edge kernel
//   - x gathered straight into A-frag registers; a,dst direct from global
//   - B: 34 frags per c-group from L2-hot w2frag; f32 a-scale on MFMA out
//   - R4 line-coalesced atomic scatter per c-group
// ============================================================================

#define PREP_ELEMS 69632
#define PREP_BLOCKS 272  // ceil(69632/256)

typedef short short8 __attribute__((ext_vector_type(8)));
typedef float floatx4 __attribute__((ext_vector_type(4)));

__device__ __forceinline__ uint32_t cvt_pk_bf16(float lo, float hi) {
  uint32_t r;
  asm("v_cvt_pk_bf16_f32 %0, %1, %2" : "=v"(r) : "v"(lo), "v"(hi));
  return r;
}

__device__ __forceinline__ uint16_t f32_to_bf16_bits(float x) {
  uint32_t u = __float_as_uint(x);
  u += 0x7fffu + ((u >> 16) & 1u);
  return (uint16_t)(u >> 16);
}

__device__ __forceinline__ float f4_get(const float4& v, int i) {
  return i == 0 ? v.x : i == 1 ? v.y : i == 2 ? v.z : v.w;
}

// K1: blocks [0,PREP_BLOCKS) build w2frag bf16 [s17][t2][c4][lane64][i8];
//     blocks [PREP_BLOCKS,...) base: out = x@(W_root+W_res) + bias+b_res.
__global__ __launch_bounds__(256) void k1_kernel(
    const float* __restrict__ x,
    const float* __restrict__ W_edge, const float* __restrict__ b_edge,
    const float* __restrict__ W_root, const float* __restrict__ bias,
    const float* __restrict__ W_res,  const float* __restrict__ b_res,
    uint16_t* __restrict__ w2frag, float* __restrict__ out, int N) {
  int tid = threadIdx.x;
  if (blockIdx.x < PREP_BLOCKS) {
    int gid = blockIdx.x * 256 + tid;
    if (gid < PREP_ELEMS) {
      int i = gid & 7, l = (gid >> 3) & 63, c = (gid >> 9) & 3;
      int t = (gid >> 11) & 1, s = gid >> 12;
      int d = t * 32 + 8 * (l >> 4) + i;
      int f = c * 16 + (l & 15);
      float v = (s < 16) ? W_edge[s * 4096 + d * 64 + f] : b_edge[d * 64 + f];
      w2frag[gid] = f32_to_bf16_bits(v);
    }
    return;
  }
  int bb = blockIdx.x - PREP_BLOCKS;
  int w = tid >> 6, l = tid & 63, l16 = l & 15, lq = l >> 4;
  union BF { short8 s8; uint16_t h[8]; } Bf[2][4];
#pragma unroll
  for (int t = 0; t < 2; ++t)
#pragma unroll
    for (int c = 0; c < 4; ++c)
#pragma unroll
      for (int i = 0; i < 8; ++i) {
        int d = t * 32 + 8 * lq + i;
        int f = c * 16 + l16;
        Bf[t][c].h[i] = f32_to_bf16_bits(W_root[d * 64 + f] + W_res[d * 64 + f]);
      }
  int arow = bb * 64 + w * 16 + l16;
  float xv[16];
#pragma unroll
  for (int t = 0; t < 2; ++t)
#pragma unroll
    for (int i = 0; i < 8; ++i)
      xv[t * 8 + i] = (arow < N) ? x[arow * 64 + t * 32 + 8 * lq + i] : 0.0f;
  union { short8 s8; uint32_t u[4]; } A[2];
#pragma unroll
  for (int t = 0; t < 2; ++t)
#pragma unroll
    for (int j = 0; j < 4; ++j)
      A[t].u[j] = cvt_pk_bf16(xv[t * 8 + 2 * j], xv[t * 8 + 2 * j + 1]);
  floatx4 acc[4];
#pragma unroll
  for (int c = 0; c < 4; ++c) acc[c] = (floatx4){0.f, 0.f, 0.f, 0.f};
#pragma unroll
  for (int t = 0; t < 2; ++t)
#pragma unroll
    for (int c = 0; c < 4; ++c)
      acc[c] = __builtin_amdgcn_mfma_f32_16x16x32_bf16(A[t].s8, Bf[t][c].s8, acc[c], 0, 0, 0);
#pragma unroll
  for (int c = 0; c < 4; ++c) {
    int f = c * 16 + l16;
    float bs = bias[f] + b_res[f];
#pragma unroll
    for (int r = 0; r < 4; ++r) {
      int row = bb * 64 + w * 16 + lq * 4 + r;
      if (row < N) out[row * 64 + f] = acc[c][r] + bs;
    }
  }
}

// edge: ONE WAVE = ONE 64-edge tile, all 64 f-cols (c-loop), zero LDS/barriers.
__global__ __launch_bounds__(256, 3) void edge_kernel(
    const float* __restrict__ x, const int* __restrict__ eidx,
    const float* __restrict__ attr, const uint16_t* __restrict__ w2frag,
    float* __restrict__ out, int E, int T) {
  int tid = threadIdx.x;
  int w = tid >> 6, l = tid & 63, l16 = l & 15, lq = l >> 4;
  int tl = blockIdx.x * 4 + w;
  if (tl >= T) return;  // wave-uniform
  int e0 = tl * 64;
  int cnt = min(64, E - e0);
  const int* srcp = eidx;
  const int* dstp = eidx + E;
  const float4* a4 = (const float4*)attr;

  // ---- A-frags: direct gather. lane l, row-group rt -> edge rt*16+l16,
  //      k-chunk t*32 + lq*8 (two float4 = 32B aligned) ----
  union AF { short8 s8; uint32_t u[4]; } A[4][2];
#pragma unroll
  for (int rt = 0; rt < 4; ++rt) {
    int er = e0 + min(rt * 16 + l16, cnt - 1);
    int sA = srcp[er];
    const float* xr = x + (size_t)sA * 64;
#pragma unroll
    for (int t = 0; t < 2; ++t) {
      float4 u = *(const float4*)(xr + t * 32 + lq * 8);
      float4 v = *(const float4*)(xr + t * 32 + lq * 8 + 4);
      A[rt][t].u[0] = cvt_pk_bf16(u.x, u.y);
      A[rt][t].u[1] = cvt_pk_bf16(u.z, u.w);
      A[rt][t].u[2] = cvt_pk_bf16(v.x, v.y);
      A[rt][t].u[3] = cvt_pk_bf16(v.z, v.w);
    }
  }

  const short8* bp = (const short8*)w2frag;

#pragma unroll 1
  for (int c = 0; c < 4; ++c) {  // f-col group: this wave does ALL of them
    floatx4 acc[4];
#pragma unroll
    for (int rt = 0; rt < 4; ++rt) acc[rt] = (floatx4){0.f, 0.f, 0.f, 0.f};

#pragma unroll
    for (int g = 0; g < 4; ++g) {
      short8 Bf[8];
#pragma unroll
      for (int sg = 0; sg < 4; ++sg) {
        int s = g * 4 + sg;
        Bf[sg * 2 + 0] = bp[((s * 2 + 0) * 4 + c) * 64 + l];
        Bf[sg * 2 + 1] = bp[((s * 2 + 1) * 4 + c) * 64 + l];
      }
#pragma unroll
      for (int rt = 0; rt < 4; ++rt) {
        float4 av[4];
#pragma unroll
        for (int r = 0; r < 4; ++r) {
          int ea = e0 + min(rt * 16 + lq * 4 + r, cnt - 1);
          av[r] = a4[ea * 4 + g];  // broadcast within 16-lane group, L1-hot
        }
#pragma unroll
        for (int sg = 0; sg < 4; ++sg) {
          floatx4 y = (floatx4){0.f, 0.f, 0.f, 0.f};
          y = __builtin_amdgcn_mfma_f32_16x16x32_bf16(A[rt][0].s8, Bf[sg * 2 + 0], y, 0, 0, 0);
          y = __builtin_amdgcn_mfma_f32_16x16x32_bf16(A[rt][1].s8, Bf[sg * 2 + 1], y, 0, 0, 0);
          acc[rt][0] += f4_get(av[0], sg) * y[0];
          acc[rt][1] += f4_get(av[1], sg) * y[1];
          acc[rt][2] += f4_get(av[2], sg) * y[2];
          acc[rt][3] += f4_get(av[3], sg) * y[3];
        }
      }
    }
    // bias slot (a == 1)
    short8 Bb0 = bp[(32 * 4 + c) * 64 + l];
    short8 Bb1 = bp[(33 * 4 + c) * 64 + l];
#pragma unroll
    for (int rt = 0; rt < 4; ++rt) {
      floatx4 y = (floatx4){0.f, 0.f, 0.f, 0.f};
      y = __builtin_amdgcn_mfma_f32_16x16x32_bf16(A[rt][0].s8, Bb0, y, 0, 0, 0);
      y = __builtin_amdgcn_mfma_f32_16x16x32_bf16(A[rt][1].s8, Bb1, y, 0, 0, 0);
      acc[rt] += y;
    }

    // line-coalesced atomic scatter: per instr 4 edges x 16 consecutive f
#pragma unroll
    for (int rt = 0; rt < 4; ++rt)
#pragma unroll
      for (int r = 0; r < 4; ++r) {
        int e = rt * 16 + lq * 4 + r;
        int d = dstp[e0 + min(e, cnt - 1)];
        if (e < cnt) atomicAdd(&out[d * 64 + c * 16 + l16], acc[rt][r]);
      }
  }
}

__global__ __launch_bounds__(256) void ln_kernel(
    float* __restrict__ out, const float* __restrict__ gamma,
    const float* __restrict__ beta, int N) {
  int w = threadIdx.x >> 6, l = threadIdx.x & 63;
  int row = blockIdx.x * 4 + w;
  if (row >= N) return;
  float v = out[row * 64 + l];
  float s = v;
#pragma unroll
  for (int m = 32; m >= 1; m >>= 1) s += __shfl_xor(s, m);
  float mu = s * 0.015625f;
  float d = v - mu;
  float q = d * d;
#pragma unroll
  for (int m = 32; m >= 1; m >>= 1) q += __shfl_xor(q, m);
  float var = q * 0.015625f;
  out[row * 64 + l] = d * rsqrtf(var + 1e-5f) * gamma[l] + beta[l];
}

extern "C" void kernel_launch(void* const* d_in, const int* in_sizes, int n_in,
                              void* d_out, int out_size, void* d_ws, size_t ws_size,
                              hipStream_t stream) {
  const float* x      = (const float*)d_in[0];
  const int*   eidx   = (const int*)d_in[1];
  const float* attr   = (const float*)d_in[2];
  const float* W_edge = (const float*)d_in[3];
  const float* b_edge = (const float*)d_in[4];
  const float* W_root = (const float*)d_in[5];
  const float* bias   = (const float*)d_in[6];
  const float* W_res  = (const float*)d_in[7];
  const float* b_res  = (const float*)d_in[8];
  const float* gamma  = (const float*)d_in[9];
  const float* beta   = (const float*)d_in[10];
  int N = in_sizes[0] / 64;
  int E = in_sizes[1] / 2;
  float* out = (float*)d_out;
  uint16_t* w2frag = (uint16_t*)d_ws;

  int G1 = PREP_BLOCKS + (N + 63) / 64;
  k1_kernel<<<G1, 256, 0, stream>>>(x, W_edge, b_edge, W_root, bias, W_res,
                                    b_res, w2frag, out, N);
  int T = (E + 63) / 64;
  edge_kernel<<<(T + 3) / 4, 256, 0, stream>>>(x, eidx, attr, w2frag, out, E, T);
  ln_kernel<<<(N + 3) / 4, 256, 0, stream>>>(out, gamma, beta, N);
}

// Round 12
// 83.665 us; speedup vs baseline: 4.5265x; 4.5265x over previous
//
#include <hip/hip_runtime.h>
#include <stdint.h>

// ============================================================================
// LaneGraphConvLayerShared: NNConv(edge-conditioned) + root + residual + LN
//
// msg[e,f] = (A_e @ W2)[f], A_e[k*64+d]=a[e,k]*x[src,d]; slot16: a=1, b_edge
//
// R11 post-mortem: barrier-free waves also failed (and spilled ~900MB).
//   Falsification sweep: B-traffic 4x (R4 vs R7), atomic-lines 3x (R8),
//   coupling (R11) -- all null. Last un-falsified common mechanism: the
//   random x-gather (256 random 64B-line events per tile).
// R12: R4 (best, 90.3us) + ONE delta: base_kernel also emits x as bf16
//   ([N][64], 128B/row) -> edge gathers from x_bf16: line events/tile
//   halve (256->128), bytes halve, 6.4MB is L2/L3-resident. Raw uint4
//   held in regs, expanded at LDS stage-write (preserves deferred-wait
//   prefetch). Fallback to exact R4 f32 path if ws too small.
// ============================================================================

#define NSLOT 17

typedef short short8 __attribute__((ext_vector_type(8)));
typedef float floatx4 __attribute__((ext_vector_type(4)));

union AFrag { short8 s8; uint32_t u[4]; };

__device__ __forceinline__ uint32_t cvt_pk_bf16(float lo, float hi) {
  uint32_t r;
  asm("v_cvt_pk_bf16_f32 %0, %1, %2" : "=v"(r) : "v"(lo), "v"(hi));
  return r;
}

__device__ __forceinline__ uint16_t f32_to_bf16_bits(float x) {
  uint32_t u = __float_as_uint(x);
  u += 0x7fffu + ((u >> 16) & 1u);
  return (uint16_t)(u >> 16);
}

__device__ __forceinline__ float bflo(uint32_t p) { return __uint_as_float(p << 16); }
__device__ __forceinline__ float bfhi(uint32_t p) { return __uint_as_float(p & 0xffff0000u); }

// ws layout:
//   [0,       139264): W2frag  bf16 [slot17][kstep2][c4][lane64][i8]
//   [139776,  147968): Wsumfrag bf16 (W_root+W_res)
//   [147968,  148224): bsum f32 [64]  (bias + b_res)
//   [148480, +N*128 ): x_bf16 [N][64]   (if ws_size permits)
#define W2FRAG_OFF 0
#define WSUM_OFF   139776
#define BSUM_OFF   147968
#define XBF_OFF    148480
#define PREP_TOTAL 73792   // 69632 + 4096 + 64

__global__ __launch_bounds__(256) void prep_kernel(
    const float* __restrict__ W_edge, const float* __restrict__ b_edge,
    const float* __restrict__ W_root, const float* __restrict__ bias,
    const float* __restrict__ W_res,  const float* __restrict__ b_res,
    uint16_t* __restrict__ w2frag, uint16_t* __restrict__ wsumfrag,
    float* __restrict__ bsum) {
  int gid = blockIdx.x * 256 + threadIdx.x;
  if (gid < 69632) {
    int i = gid & 7, l = (gid >> 3) & 63, c = (gid >> 9) & 3;
    int t = (gid >> 11) & 1, s = gid >> 12;
    int d = t * 32 + 8 * (l >> 4) + i;
    int f = c * 16 + (l & 15);
    float v = (s < 16) ? W_edge[s * 4096 + d * 64 + f] : b_edge[d * 64 + f];
    w2frag[gid] = f32_to_bf16_bits(v);
  } else if (gid < 73728) {
    int g = gid - 69632;
    int i = g & 7, l = (g >> 3) & 63, c = (g >> 9) & 3, t = (g >> 11) & 1;
    int d = t * 32 + 8 * (l >> 4) + i;
    int f = c * 16 + (l & 15);
    wsumfrag[g] = f32_to_bf16_bits(W_root[d * 64 + f] + W_res[d * 64 + f]);
  } else if (gid < PREP_TOTAL) {
    int f = gid - 73728;
    bsum[f] = bias[f] + b_res[f];
  }
}

// base: out = x@(W_root+W_res) + bias+b_res; optionally also emits x_bf16.
__global__ __launch_bounds__(256) void base_kernel(
    const float* __restrict__ x, const uint16_t* __restrict__ wsumfrag,
    const float* __restrict__ bsum, float* __restrict__ out,
    uint16_t* __restrict__ xbf, int N) {
  int w = threadIdx.x >> 6, l = threadIdx.x & 63;
  int l16 = l & 15, lq = l >> 4;
  int arow = blockIdx.x * 64 + w * 16 + l16;
  float xv[16];
#pragma unroll
  for (int t = 0; t < 2; ++t)
#pragma unroll
    for (int i = 0; i < 8; ++i)
      xv[t * 8 + i] = (arow < N) ? x[arow * 64 + t * 32 + 8 * lq + i] : 0.0f;
  AFrag A[2];
#pragma unroll
  for (int t = 0; t < 2; ++t)
#pragma unroll
    for (int j = 0; j < 4; ++j)
      A[t].u[j] = cvt_pk_bf16(xv[t * 8 + 2 * j], xv[t * 8 + 2 * j + 1]);
  if (xbf != nullptr && arow < N) {
#pragma unroll
    for (int t = 0; t < 2; ++t) {
      uint4 c;
      c.x = A[t].u[0];
      c.y = A[t].u[1];
      c.z = A[t].u[2];
      c.w = A[t].u[3];
      *(uint4*)(xbf + arow * 64 + t * 32 + lq * 8) = c;
    }
  }
  floatx4 acc[4];
#pragma unroll
  for (int c = 0; c < 4; ++c) acc[c] = (floatx4){0.f, 0.f, 0.f, 0.f};
  const short8* bp = (const short8*)wsumfrag;
#pragma unroll
  for (int t = 0; t < 2; ++t)
#pragma unroll
    for (int c = 0; c < 4; ++c) {
      short8 B = bp[(t * 4 + c) * 64 + l];
      acc[c] = __builtin_amdgcn_mfma_f32_16x16x32_bf16(A[t].s8, B, acc[c], 0, 0, 0);
    }
#pragma unroll
  for (int c = 0; c < 4; ++c) {
    int f = c * 16 + l16;
    float bs = bsum[f];
#pragma unroll
    for (int r = 0; r < 4; ++r) {
      int row = blockIdx.x * 64 + w * 16 + lq * 4 + r;
      if (row < N) out[row * 64 + f] = acc[c][r] + bs;
    }
  }
}

// edge: R4 structure verbatim. XBF=1 gathers x from bf16 (half the random
// line events); XBF=0 is the exact R4 f32 path.
template <int XBF>
__global__ __launch_bounds__(256, 2) void edge_kernel(
    const float* __restrict__ x, const uint16_t* __restrict__ xbf,
    const int* __restrict__ eidx, const float* __restrict__ attr,
    const uint16_t* __restrict__ w2frag, float* __restrict__ out, int E) {
  __shared__ float x_lds[64][68];
  __shared__ float a_lds[64][17];
  __shared__ int   dst_lds[64];
  __shared__ float red[4][32][68];

  int tid = threadIdx.x;
  int w = tid >> 6, l = tid & 63, l16 = l & 15, lq = l >> 4;
  int row = tid >> 2, q = tid & 3;
  const int* srcp = eidx;
  const int* dstp = eidx + E;
  const float4* x4 = (const float4*)x;
  const uint4* xs4 = (const uint4*)xbf;
  const float4* a4 = (const float4*)attr;
  int T = (E + 63) >> 6;
  const short8* bp = (const short8*)w2frag;

  short8 Breg[4][2][4];
#pragma unroll
  for (int si = 0; si < 4; ++si) {
    int s = 4 * si + w;
#pragma unroll
    for (int t = 0; t < 2; ++t)
#pragma unroll
      for (int c = 0; c < 4; ++c)
        Breg[si][t][c] = bp[((s * 2 + t) * 4 + c) * 64 + l];
  }
  int tx = w - 2;  // waves 2,3 take K-halves of bias slot 16
  short8 Bx[4];
  if (tx >= 0) {
#pragma unroll
    for (int c = 0; c < 4; ++c) Bx[c] = bp[((32 + tx) * 4 + c) * 64 + l];
  }

  // ---- stage first tile ----
  int tl = blockIdx.x;
  if (tl < T) {
    int cnt0 = min(64, E - tl * 64);
    bool ok = row < cnt0;
    int sidx = ok ? srcp[tl * 64 + row] : 0;
    if (XBF) {
      uint4 u0 = make_uint4(0, 0, 0, 0), u1 = make_uint4(0, 0, 0, 0);
      if (ok) { u0 = xs4[sidx * 8 + q * 2]; u1 = xs4[sidx * 8 + q * 2 + 1]; }
      uint32_t uu[8] = {u0.x, u0.y, u0.z, u0.w, u1.x, u1.y, u1.z, u1.w};
#pragma unroll
      for (int j = 0; j < 4; ++j) {
        float4 v = make_float4(bflo(uu[2 * j]), bfhi(uu[2 * j]),
                               bflo(uu[2 * j + 1]), bfhi(uu[2 * j + 1]));
        *(float4*)&x_lds[row][q * 16 + j * 4] = v;
      }
    } else {
#pragma unroll
      for (int j = 0; j < 4; ++j) {
        float4 v = make_float4(0.f, 0.f, 0.f, 0.f);
        if (ok) v = x4[sidx * 16 + q * 4 + j];
        *(float4*)&x_lds[row][q * 16 + j * 4] = v;
      }
    }
    float4 av = make_float4(0.f, 0.f, 0.f, 0.f);
    if (ok) av = a4[(tl * 64 + row) * 4 + q];
    a_lds[row][q * 4 + 0] = av.x;
    a_lds[row][q * 4 + 1] = av.y;
    a_lds[row][q * 4 + 2] = av.z;
    a_lds[row][q * 4 + 3] = av.w;
    if (q == 0) a_lds[row][16] = 1.0f;
    if (tid < 64) dst_lds[tid] = (tid < cnt0) ? dstp[tl * 64 + tid] : 0;
  }
  __syncthreads();

  for (; tl < T; tl += gridDim.x) {
    int cnt = min(64, E - tl * 64);
    int nxt = tl + (int)gridDim.x;
    bool havenxt = nxt < T;
    // early-issue next tile's gather; raw words held, expanded at stage-write
    float4 xr[4];
    uint4 xu0 = make_uint4(0, 0, 0, 0), xu1 = make_uint4(0, 0, 0, 0);
    float4 ar = make_float4(0.f, 0.f, 0.f, 0.f);
    int dv = 0;
    if (havenxt) {
      int cntn = min(64, E - nxt * 64);
      bool ok = row < cntn;
      int sidx = ok ? srcp[nxt * 64 + row] : 0;
      if (XBF) {
        if (ok) { xu0 = xs4[sidx * 8 + q * 2]; xu1 = xs4[sidx * 8 + q * 2 + 1]; }
      } else {
#pragma unroll
        for (int j = 0; j < 4; ++j) {
          xr[j] = make_float4(0.f, 0.f, 0.f, 0.f);
          if (ok) xr[j] = x4[sidx * 16 + q * 4 + j];
        }
      }
      if (ok) ar = a4[(nxt * 64 + row) * 4 + q];
      if (ok) dv = dstp[nxt * 64 + row];
    }

#pragma unroll
    for (int p = 0; p < 2; ++p) {
      floatx4 acc[2][4];
#pragma unroll
      for (int rt = 0; rt < 2; ++rt)
#pragma unroll
        for (int c = 0; c < 4; ++c) acc[rt][c] = (floatx4){0.f, 0.f, 0.f, 0.f};

#pragma unroll
      for (int rt = 0; rt < 2; ++rt) {
        int arow = p * 32 + rt * 16 + l16;
        float xv[16];
#pragma unroll
        for (int t2 = 0; t2 < 2; ++t2)
#pragma unroll
          for (int i = 0; i < 8; ++i)
            xv[t2 * 8 + i] = x_lds[arow][t2 * 32 + 8 * lq + i];
#pragma unroll
        for (int si = 0; si < 4; ++si) {
          float av = a_lds[arow][4 * si + w];
#pragma unroll
          for (int t = 0; t < 2; ++t) {
            AFrag A;
#pragma unroll
            for (int j = 0; j < 4; ++j)
              A.u[j] = cvt_pk_bf16(av * xv[t * 8 + 2 * j], av * xv[t * 8 + 2 * j + 1]);
#pragma unroll
            for (int c = 0; c < 4; ++c)
              acc[rt][c] = __builtin_amdgcn_mfma_f32_16x16x32_bf16(
                  A.s8, Breg[si][t][c], acc[rt][c], 0, 0, 0);
          }
        }
        if (tx >= 0) {  // bias slot, a == 1, K-half tx
          AFrag A;
#pragma unroll
          for (int j = 0; j < 4; ++j)
            A.u[j] = cvt_pk_bf16(xv[tx * 8 + 2 * j], xv[tx * 8 + 2 * j + 1]);
#pragma unroll
          for (int c = 0; c < 4; ++c)
            acc[rt][c] = __builtin_amdgcn_mfma_f32_16x16x32_bf16(
                A.s8, Bx[c], acc[rt][c], 0, 0, 0);
        }
      }

      // partial -> LDS
#pragma unroll
      for (int rt = 0; rt < 2; ++rt)
#pragma unroll
        for (int c = 0; c < 4; ++c) {
          int f = c * 16 + l16;
#pragma unroll
          for (int r = 0; r < 4; ++r)
            red[w][rt * 16 + lq * 4 + r][f] = acc[rt][c][r];
        }
      __syncthreads();

      // cross-wave reduce + LINE-COALESCED atomic scatter (R4-verified)
#pragma unroll
      for (int c = 0; c < 4; ++c) {
        int f = c * 16 + l16;
#pragma unroll
        for (int r = 0; r < 2; ++r) {
          int rr = w * 8 + lq * 2 + r;
          float s = red[0][rr][f] + red[1][rr][f] + red[2][rr][f] + red[3][rr][f];
          int grow = p * 32 + rr;
          if (grow < cnt) atomicAdd(&out[dst_lds[grow] * 64 + f], s);
        }
      }
      __syncthreads();
    }

    // stage next tile (all reads of current tile complete)
    if (havenxt) {
      if (XBF) {
        uint32_t uu[8] = {xu0.x, xu0.y, xu0.z, xu0.w, xu1.x, xu1.y, xu1.z, xu1.w};
#pragma unroll
        for (int j = 0; j < 4; ++j) {
          float4 v = make_float4(bflo(uu[2 * j]), bfhi(uu[2 * j]),
                                 bflo(uu[2 * j + 1]), bfhi(uu[2 * j + 1]));
          *(float4*)&x_lds[row][q * 16 + j * 4] = v;
        }
      } else {
#pragma unroll
        for (int j = 0; j < 4; ++j) *(float4*)&x_lds[row][q * 16 + j * 4] = xr[j];
      }
      a_lds[row][q * 4 + 0] = ar.x;
      a_lds[row][q * 4 + 1] = ar.y;
      a_lds[row][q * 4 + 2] = ar.z;
      a_lds[row][q * 4 + 3] = ar.w;
      if (q == 0) dst_lds[row] = dv;
    }
    __syncthreads();
  }
}

__global__ __launch_bounds__(256) void ln_kernel(
    float* __restrict__ out, const float* __restrict__ gamma,
    const float* __restrict__ beta, int N) {
  int w = threadIdx.x >> 6, l = threadIdx.x & 63;
  int row = blockIdx.x * 4 + w;
  if (row >= N) return;
  float v = out[row * 64 + l];
  float s = v;
#pragma unroll
  for (int m = 32; m >= 1; m >>= 1) s += __shfl_xor(s, m);
  float mu = s * 0.015625f;
  float d = v - mu;
  float q = d * d;
#pragma unroll
  for (int m = 32; m >= 1; m >>= 1) q += __shfl_xor(q, m);
  float var = q * 0.015625f;
  out[row * 64 + l] = d * rsqrtf(var + 1e-5f) * gamma[l] + beta[l];
}

extern "C" void kernel_launch(void* const* d_in, const int* in_sizes, int n_in,
                              void* d_out, int out_size, void* d_ws, size_t ws_size,
                              hipStream_t stream) {
  const float* x      = (const float*)d_in[0];
  const int*   eidx   = (const int*)d_in[1];
  const float* attr   = (const float*)d_in[2];
  const float* W_edge = (const float*)d_in[3];
  const float* b_edge = (const float*)d_in[4];
  const float* W_root = (const float*)d_in[5];
  const float* bias   = (const float*)d_in[6];
  const float* W_res  = (const float*)d_in[7];
  const float* b_res  = (const float*)d_in[8];
  const float* gamma  = (const float*)d_in[9];
  const float* beta   = (const float*)d_in[10];
  int N = in_sizes[0] / 64;
  int E = in_sizes[1] / 2;
  float* out = (float*)d_out;
  uint16_t* w2frag   = (uint16_t*)((char*)d_ws + W2FRAG_OFF);
  uint16_t* wsumfrag = (uint16_t*)((char*)d_ws + WSUM_OFF);
  float*    bsum     = (float*)((char*)d_ws + BSUM_OFF);

  size_t need = (size_t)XBF_OFF + (size_t)N * 128;
  bool usebf = ws_size >= need;
  uint16_t* xbf = usebf ? (uint16_t*)((char*)d_ws + XBF_OFF) : nullptr;

  prep_kernel<<<(PREP_TOTAL + 255) / 256, 256, 0, stream>>>(
      W_edge, b_edge, W_root, bias, W_res, b_res, w2frag, wsumfrag, bsum);
  base_kernel<<<(N + 63) / 64, 256, 0, stream>>>(x, wsumfrag, bsum, out, xbf, N);
  int T = (E + 63) / 64;
  int G = T < 512 ? T : 512;
  if (usebf)
    edge_kernel<1><<<G, 256, 0, stream>>>(x, xbf, eidx, attr, w2frag, out, E);
  else
    edge_kernel<0><<<G, 256, 0, stream>>>(x, xbf, eidx, attr, w2frag, out, E);
  ln_kernel<<<(N + 3) / 4, 256, 0, stream>>>(out, gamma, beta, N);
}